// Round 5
// baseline (563.059 us; speedup 1.0000x reference)
//
#include <hip/hip_runtime.h>
#include <hip/hip_bf16.h>
#include <stdint.h>

#define N_NODES 100000
#define DEG 16
#define D_IN 128
#define D_OUT 256
#define K_TOP 32
#define K_CAT 256   // concatenated K = D_IN(self) + D_IN(neigh)

typedef __attribute__((ext_vector_type(8))) short short8;
typedef __attribute__((ext_vector_type(4))) float floatx4;

__device__ __forceinline__ unsigned pack_bf16_rne(float f) {
    union { float f; unsigned u; } c; c.f = f;
    unsigned u = c.u;
    return (u + 0x7fffu + ((u >> 16) & 1u)) >> 16;   // round-to-nearest-even
}
__device__ __forceinline__ float bf16lo_to_f(unsigned lo16) {
    union { unsigned u; float f; } c; c.u = lo16 << 16; return c.f;
}

// async global->LDS, 16B per lane; LDS dest is wave-uniform base + lane*16
typedef __attribute__((address_space(1))) void as1_void;
typedef __attribute__((address_space(3))) void as3_void;
__device__ __forceinline__ void gload_lds16(const void* g, void* l) {
    __builtin_amdgcn_global_load_lds((as1_void*)g, (as3_void*)l, 16, 0, 0);
}

// scatter 4 (val,idx) pairs: vlo holds vals 2k,2k+1; vhi vals 2k+2,2k+3; id 4 u8 idx
__device__ __forceinline__ void scat4(float* __restrict__ arow, float ew,
                                      unsigned vlo, unsigned vhi, unsigned id) {
    atomicAdd(&arow[ id        & 255u], ew * bf16lo_to_f(vlo & 0xffffu));
    atomicAdd(&arow[(id >>  8) & 255u], ew * bf16lo_to_f(vlo >> 16));
    atomicAdd(&arow[(id >> 16) & 255u], ew * bf16lo_to_f(vhi & 0xffffu));
    atomicAdd(&arow[ id >> 24        ], ew * bf16lo_to_f(vhi >> 16));
}
// one edge's full record: 4 val-quads + 2 idx-quads (function, not macro: a macro
// parameter named `w` would capture the `.w` member-access token — round-4 bug)
__device__ __forceinline__ void scat_edge(float* __restrict__ arow, float ew,
                                          uint4 r0, uint4 r1, uint4 r2, uint4 r3,
                                          uint4 ia, uint4 ib) {
    scat4(arow, ew, r0.x, r0.y, ia.x);
    scat4(arow, ew, r0.z, r0.w, ia.y);
    scat4(arow, ew, r1.x, r1.y, ia.z);
    scat4(arow, ew, r1.z, r1.w, ia.w);
    scat4(arow, ew, r2.x, r2.y, ib.x);
    scat4(arow, ew, r2.z, r2.w, ib.y);
    scat4(arow, ew, r3.x, r3.y, ib.z);
    scat4(arow, ew, r3.z, r3.w, ib.w);
}

// ---------------- kernel 1 (merged prep): feat->bf16 | topk pack | weight pack ---------
// Packed top-k record per node: 96 B = bf16 vals[32] (64B) + u8 idx[32] (32B).
#define FEAT_BLKS 1563   // ceil(N/64)
#define PACK_BLKS 1563

__global__ __launch_bounds__(256) void k_prep(const float* __restrict__ feat,
                                              const float* __restrict__ topk_v,
                                              const int* __restrict__ topk_i,
                                              const float* __restrict__ w_self,
                                              const float* __restrict__ w_neigh,
                                              unsigned short* __restrict__ fbf,
                                              unsigned char* __restrict__ pkrec,
                                              unsigned short* __restrict__ bmat) {
    const int t = threadIdx.x;
    const int bid = blockIdx.x;
    if (bid < FEAT_BLKS) {
        // feat f32 -> fbf bf16, 64 rows/block, stride 128
        const int row0 = bid * 64;
        #pragma unroll
        for (int p = 0; p < 8; ++p) {
            int q = t + p * 256;             // 0..2047
            int r = q >> 5;                  // 0..63
            int c4 = (q & 31) * 4;
            if (row0 + r < N_NODES) {
                float4 f = *(const float4*)(feat + (size_t)(row0 + r) * D_IN + c4);
                uint2 pv;
                pv.x = pack_bf16_rne(f.x) | (pack_bf16_rne(f.y) << 16);
                pv.y = pack_bf16_rne(f.z) | (pack_bf16_rne(f.w) << 16);
                ((uint2*)(fbf + (size_t)(row0 + r) * D_IN))[q & 31] = pv;
            }
        }
    } else if (bid < FEAT_BLKS + PACK_BLKS) {
        // pack topk: 64 nodes/block, 4 threads/node, 8 (val,idx) pairs each
        const int n = (bid - FEAT_BLKS) * 64 + (t >> 2);
        const int p = t & 3;
        if (n < N_NODES) {
            const float* vs = topk_v + (size_t)n * K_TOP + p * 8;
            float4 v0 = ((const float4*)vs)[0];
            float4 v1 = ((const float4*)vs)[1];
            const int* is = topk_i + (size_t)n * K_TOP + p * 8;
            int4 i0 = ((const int4*)is)[0];
            int4 i1 = ((const int4*)is)[1];
            uint4 pv;
            pv.x = pack_bf16_rne(v0.x) | (pack_bf16_rne(v0.y) << 16);
            pv.y = pack_bf16_rne(v0.z) | (pack_bf16_rne(v0.w) << 16);
            pv.z = pack_bf16_rne(v1.x) | (pack_bf16_rne(v1.y) << 16);
            pv.w = pack_bf16_rne(v1.z) | (pack_bf16_rne(v1.w) << 16);
            uint2 pi;
            pi.x = (unsigned)i0.x | ((unsigned)i0.y << 8) | ((unsigned)i0.z << 16) | ((unsigned)i0.w << 24);
            pi.y = (unsigned)i1.x | ((unsigned)i1.y << 8) | ((unsigned)i1.z << 16) | ((unsigned)i1.w << 24);
            unsigned char* rec = pkrec + (size_t)n * 96;
            *(uint4*)(rec + p * 16) = pv;
            *(uint2*)(rec + 64 + p * 8) = pi;
        }
    } else {
        // pack [w_self | w_neigh] -> bf16 B[256][256]
        const int o = bid - (FEAT_BLKS + PACK_BLKS);   // 0..255
        const int k = t;
        float v = (k < D_IN) ? w_self[o * D_IN + k] : w_neigh[o * D_IN + (k - D_IN)];
        bmat[o * K_CAT + k] = (unsigned short)pack_bf16_rne(v);
    }
}

// ------ kernel 2 (fused): sparse scatter-aggregate in LDS, then GEMM over K=256 --------
// Phase 1 (MLP-restructured): ONE LANE PER EDGE. Each thread owns 2 edges per 64-row
// pass; cols/weights loaded up-front (coalesced), then 12 independent uint4 record
// loads in flight BEFORE any atomic; then 64 ds_add_f32 scatters in one batch.
// Invalid tail edges get w=0 -> no-op adds.
// Phase 2: verified round-2 GEMM loop (BM=128, BN=256, BK=32, 8 waves 2x4,
// swapped-operand mfma_f32_16x16x32_bf16, float4 epilogue).
// LDS aliasing: aggf32 (32K) overlaps As[0..1]+Bs[0]; Bs[1] free -> kt=0 B prefetch
// issues at kernel start.
#define BM 128
#define BN 256
#define BK 32
#define NTA 4
#define NT  8

__global__ __launch_bounds__(512, 4) void k_fused(const float* __restrict__ csr_w,
                                                  const int* __restrict__ col_idx,
                                                  const unsigned char* __restrict__ pkrec,
                                                  const unsigned short* __restrict__ fbf,
                                                  const unsigned short* __restrict__ bmat,
                                                  const float* __restrict__ bias,
                                                  float* __restrict__ out) {
    __shared__ __align__(16) char smem[81920];                               // 80 KiB
    unsigned short* aggbf = (unsigned short*)smem;                           // [128][128] swizzled, 32K
    float* aggf = (float*)(smem + 32768);                                    // [64][128] f32, 32K (aliased)
    unsigned short (*As)[BM * BK] = (unsigned short (*)[BM * BK])(smem + 32768);   // 2 x 8K
    unsigned short (*Bs)[BN * BK] = (unsigned short (*)[BN * BK])(smem + 49152);   // 2 x 16K

    const int t = threadIdx.x;
    const int lane = t & 63, wave = t >> 6;
    const int l16 = lane & 15, quad = lane >> 4;
    const int row0 = blockIdx.x * BM;

    // staging geometry: wave covers 16 rows x 4x16B chunks, linear LDS
    const int a_r = wave * 16 + (lane >> 2);
    const int a_c = (lane & 3) * 8;                          // shorts
    int a_gr = row0 + a_r; if (a_gr >= N_NODES) a_gr = N_NODES - 1;   // clamp: never stored
    const unsigned short* gA  = fbf  + (size_t)a_gr * D_IN + a_c;
    const unsigned short* gB0 = bmat + (size_t)a_r        * K_CAT + a_c;
    const unsigned short* gB1 = bmat + (size_t)(a_r + 128) * K_CAT + a_c;

#define STAGE_A(buf, tt) gload_lds16(gA + (tt) * BK, &As[buf][wave * 16 * BK])
#define STAGE_B(buf, tt) do {                                                 \
        gload_lds16(gB0 + (tt) * BK, &Bs[buf][(wave * 16)       * BK]);       \
        gload_lds16(gB1 + (tt) * BK, &Bs[buf][(wave * 16 + 128) * BK]);       \
    } while (0)

    STAGE_B(1, 0);   // Bs[1] does not alias aggf32 -> safe to fly during phase 1

    // ---- phase 1 setup: all 4 edges' (col, w) up-front, coalesced & guarded ----
    int   c00, c01, c10, c11;
    float w00, w01, w10, w11;
    {
        const int eb = row0 * DEG;
        int ok00 = (row0 +       ( t        >> 4)) < N_NODES;
        int ok01 = (row0 +       ((t + 512) >> 4)) < N_NODES;
        int ok10 = (row0 + 64 +  ( t        >> 4)) < N_NODES;
        int ok11 = (row0 + 64 +  ((t + 512) >> 4)) < N_NODES;
        c00 = ok00 ? col_idx[eb +        t] : 0;  w00 = ok00 ? csr_w[eb +        t] : 0.f;
        c01 = ok01 ? col_idx[eb +  512 + t] : 0;  w01 = ok01 ? csr_w[eb +  512 + t] : 0.f;
        c10 = ok10 ? col_idx[eb + 1024 + t] : 0;  w10 = ok10 ? csr_w[eb + 1024 + t] : 0.f;
        c11 = ok11 ? col_idx[eb + 1536 + t] : 0;  w11 = ok11 ? csr_w[eb + 1536 + t] : 0.f;
    }
    float* const ar0 = aggf + ( t        >> 4) * D_IN;   // rows 0..31 of pass
    float* const ar1 = aggf + ((t + 512) >> 4) * D_IN;   // rows 32..63 of pass

    // issue pass-0's 12 record loads NOW; latency hides under LDS zeroing
    const uint4* r0 = (const uint4*)(pkrec + (size_t)c00 * 96);
    const uint4* r1 = (const uint4*)(pkrec + (size_t)c01 * 96);
    uint4 p0a = r0[0], p0b = r0[1], p0c = r0[2], p0d = r0[3], p0i = r0[4], p0j = r0[5];
    uint4 p1a = r1[0], p1b = r1[1], p1c = r1[2], p1d = r1[3], p1i = r1[4], p1j = r1[5];

    // zero aggf32: 8192 floats / 512 thr = 4 float4 each
    #pragma unroll
    for (int p = 0; p < 4; ++p)
        *(floatx4*)&aggf[(t + p * 512) * 4] = (floatx4){0.f, 0.f, 0.f, 0.f};
    __syncthreads();

    // ---- pass 0: scatter rows [row0, row0+64) ----
    scat_edge(ar0, w00, p0a, p0b, p0c, p0d, p0i, p0j);
    scat_edge(ar1, w01, p1a, p1b, p1c, p1d, p1i, p1j);
    __syncthreads();

    // issue pass-1's record loads; latency hides under pass-0 pack
    const uint4* r2 = (const uint4*)(pkrec + (size_t)c10 * 96);
    const uint4* r3 = (const uint4*)(pkrec + (size_t)c11 * 96);
    uint4 q0a = r2[0], q0b = r2[1], q0c = r2[2], q0d = r2[3], q0i = r2[4], q0j = r2[5];
    uint4 q1a = r3[0], q1b = r3[1], q1c = r3[2], q1d = r3[3], q1i = r3[4], q1j = r3[5];

    // pack pass-0 aggf -> aggbf rows [0,64), XOR-swizzled; re-zero behind
    #pragma unroll
    for (int s = 0; s < 8; ++s) {
        int d  = s * 512 + t;            // dword 0..4095
        int lr = d >> 6;                 // 0..63
        int c2 = (d & 63) * 2;
        float2 v = *(const float2*)&aggf[lr * D_IN + c2];
        *(unsigned*)&aggbf[lr * D_IN + (c2 ^ ((lr & 7) << 3))] =
            pack_bf16_rne(v.x) | (pack_bf16_rne(v.y) << 16);
        *(float2*)&aggf[lr * D_IN + c2] = make_float2(0.f, 0.f);
    }
    __syncthreads();

    // ---- pass 1: scatter rows [row0+64, row0+128) ----
    scat_edge(ar0, w10, q0a, q0b, q0c, q0d, q0i, q0j);
    scat_edge(ar1, w11, q1a, q1b, q1c, q1d, q1i, q1j);
    __syncthreads();

    // pack pass-1 -> aggbf rows [64,128)
    #pragma unroll
    for (int s = 0; s < 8; ++s) {
        int d  = s * 512 + t;
        int lr = d >> 6;
        int c2 = (d & 63) * 2;
        float2 v = *(const float2*)&aggf[lr * D_IN + c2];
        int R = 64 + lr;
        *(unsigned*)&aggbf[R * D_IN + (c2 ^ ((R & 7) << 3))] =
            pack_bf16_rne(v.x) | (pack_bf16_rne(v.y) << 16);
    }

    // aggf32 dead from here; As/Bs[0] regions now usable
    STAGE_A(0, 0);

    floatx4 acc[4][4];
    #pragma unroll
    for (int i = 0; i < 4; ++i)
        #pragma unroll
        for (int j = 0; j < 4; ++j)
            acc[i][j] = (floatx4){0.f, 0.f, 0.f, 0.f};

    __syncthreads();   // drains vmcnt: As[0]/Bs[1] staged, aggbf visible

    // ---- phase 2: GEMM K-loop (B read buffer = cur^1 so kt0 uses early Bs[1]) ----
    const int wr = wave >> 2, wc = wave & 3;                 // 2x4 wave grid, 64x64 each
    #pragma unroll
    for (int tt = 0; tt < NT; ++tt) {
        const int cur = tt & 1;
        if (tt + 1 < NTA) STAGE_A(cur ^ 1, tt + 1);          // prefetch next A (fbf half)
        if (tt + 1 < NT)  STAGE_B(cur, tt + 1);              // prefetch next B (into read^1)

        short8 afr[4], bfr[4];
        if (tt < NTA) {
            #pragma unroll
            for (int i = 0; i < 4; ++i)
                afr[i] = *(const short8*)&As[cur][(wr * 64 + i * 16 + l16) * BK + quad * 8];
        } else {
            const int c0 = (tt - NTA) * 32 + quad * 8;
            #pragma unroll
            for (int i = 0; i < 4; ++i) {
                const int m = wr * 64 + i * 16 + l16;
                afr[i] = *(const short8*)&aggbf[m * 128 + (c0 ^ ((m & 7) << 3))];
            }
        }
        #pragma unroll
        for (int j = 0; j < 4; ++j)
            bfr[j] = *(const short8*)&Bs[cur ^ 1][(wc * 64 + j * 16 + l16) * BK + quad * 8];

        #pragma unroll
        for (int i = 0; i < 4; ++i)
            #pragma unroll
            for (int j = 0; j < 4; ++j)   // swapped: out-rows <- afr lanes, out-cols <- bfr regs
                acc[i][j] = __builtin_amdgcn_mfma_f32_16x16x32_bf16(bfr[j], afr[i], acc[i][j], 0, 0, 0);

        if (tt + 1 < NT) __syncthreads();
    }

    // epilogue: lane holds row m = l16 (+16i+64wr), cols quad*4..+3 (+16j+64wc) -> float4
    #pragma unroll
    for (int j = 0; j < 4; ++j) {
        const int cg = wc * 64 + j * 16 + quad * 4;
        const float4 bv = *(const float4*)&bias[cg];
        #pragma unroll
        for (int i = 0; i < 4; ++i) {
            const int gr = row0 + wr * 64 + i * 16 + l16;
            if (gr < N_NODES) {
                float4 v;
                v.x = acc[i][j][0] + bv.x;
                v.y = acc[i][j][1] + bv.y;
                v.z = acc[i][j][2] + bv.z;
                v.w = acc[i][j][3] + bv.w;
                *(float4*)(out + (size_t)gr * D_OUT + cg) = v;
            }
        }
    }
#undef STAGE_A
#undef STAGE_B
}

extern "C" void kernel_launch(void* const* d_in, const int* in_sizes, int n_in,
                              void* d_out, int out_size, void* d_ws, size_t ws_size,
                              hipStream_t stream) {
    const float* feat    = (const float*)d_in[0];
    const float* topk_v  = (const float*)d_in[1];
    const float* csr_w   = (const float*)d_in[2];
    const float* w_neigh = (const float*)d_in[3];
    const float* w_self  = (const float*)d_in[4];
    const float* b_self  = (const float*)d_in[5];
    const int*   topk_i  = (const int*)d_in[6];
    // d_in[7] = indptr (fixed degree 16, unused), d_in[8] = indices
    const int*   indices = (const int*)d_in[8];
    float* out = (float*)d_out;

    // workspace layout: fbf bf16[N*128] (25.6MB) | pkrec u8[N*96] (9.6MB) | bmat bf16[256*256]
    unsigned char* base = (unsigned char*)d_ws;
    unsigned short* fbf   = (unsigned short*)base;
    unsigned char*  pkrec = base + (size_t)N_NODES * D_IN * 2;
    unsigned short* bmat  = (unsigned short*)(pkrec + (size_t)N_NODES * 96);

    k_prep<<<dim3(FEAT_BLKS + PACK_BLKS + 256), dim3(256), 0, stream>>>(
        feat, topk_v, topk_i, w_self, w_neigh, fbf, pkrec, bmat);
    k_fused<<<dim3((N_NODES + BM - 1) / BM), dim3(512), 0, stream>>>(
        csr_w, indices, pkrec, fbf, bmat, b_self, out);
}

// Round 7
// 278.298 us; speedup vs baseline: 2.0232x; 2.0232x over previous
//
#include <hip/hip_runtime.h>
#include <hip/hip_bf16.h>
#include <stdint.h>

#define N_NODES 100000
#define DEG 16
#define D_IN 128
#define D_OUT 256
#define K_TOP 32
#define K_CAT 256   // concatenated K = D_IN(self) + D_IN(neigh)

typedef __attribute__((ext_vector_type(8))) short short8;
typedef __attribute__((ext_vector_type(4))) float floatx4;

__device__ __forceinline__ unsigned pack_bf16_rne(float f) {
    union { float f; unsigned u; } c; c.f = f;
    unsigned u = c.u;
    return (u + 0x7fffu + ((u >> 16) & 1u)) >> 16;   // round-to-nearest-even
}
__device__ __forceinline__ float bf16lo_to_f(unsigned lo16) {
    union { unsigned u; float f; } c; c.u = lo16 << 16; return c.f;
}

// async global->LDS, 16B per lane; LDS dest is wave-uniform base + lane*16
typedef __attribute__((address_space(1))) void as1_void;
typedef __attribute__((address_space(3))) void as3_void;
__device__ __forceinline__ void gload_lds16(const void* g, void* l) {
    __builtin_amdgcn_global_load_lds((as1_void*)g, (as3_void*)l, 16, 0, 0);
}

// ---------------- kernel 1: pack [w_self | w_neigh] -> bf16 B[256][256] ----------------
__global__ __launch_bounds__(256) void k_packw(const float* __restrict__ w_self,
                                               const float* __restrict__ w_neigh,
                                               unsigned short* __restrict__ bmat) {
    int o = blockIdx.x;      // 0..255 output channel
    int k = threadIdx.x;     // 0..255 concat-K
    float v = (k < D_IN) ? w_self[o * D_IN + k] : w_neigh[o * D_IN + (k - D_IN)];
    bmat[o * K_CAT + k] = (unsigned short)pack_bf16_rne(v);
}

// ------------- kernel 2: densify via LDS ds_add_f32 scatter + feat->bf16 ---------------
// Writes xbf[N][128] (dense top-k features) and fbf[N][128] (feat as bf16, stride 128).
#define DROWS 64
__global__ __launch_bounds__(256) void k_densify(const float* __restrict__ topk_v,
                                                 const int* __restrict__ topk_i,
                                                 const float* __restrict__ feat,
                                                 unsigned short* __restrict__ xbf,
                                                 unsigned short* __restrict__ fbf) {
    __shared__ float sx[DROWS * D_IN];   // 32 KiB
    const int t = threadIdx.x;
    const int row0 = blockIdx.x * DROWS;

    // zero LDS: 8192 floats / 256 thr = 8 float4 per thread
    #pragma unroll
    for (int p = 0; p < 8; ++p)
        *(floatx4*)&sx[(t + p * 256) * 4] = (floatx4){0.f, 0.f, 0.f, 0.f};
    __syncthreads();

    // scatter: 64 rows x 32 pairs = 2048 pairs, 8 per thread, coalesced reads
    const size_t tbase = (size_t)row0 * K_TOP;
    #pragma unroll
    for (int p = 0; p < 8; ++p) {
        int q = t + p * 256;             // 0..2047
        int r = q >> 5;                  // 0..63
        if (row0 + r < N_NODES) {
            int   ci = topk_i[tbase + q];
            float cv = topk_v[tbase + q];
            atomicAdd(&sx[r * D_IN + ci], cv);   // ds_add_f32, no return
        }
    }
    __syncthreads();

    // pack x -> bf16, coalesced: 4096 dwords, 16 per thread
    #pragma unroll
    for (int p = 0; p < 16; ++p) {
        int d = t + p * 256;             // dword index 0..4095
        int r = d >> 6;                  // 0..63
        int c2 = (d & 63) * 2;
        if (row0 + r < N_NODES) {
            float2 v = *(const float2*)&sx[r * D_IN + c2];
            ((unsigned*)(xbf + (size_t)(row0 + r) * D_IN))[d & 63] =
                pack_bf16_rne(v.x) | (pack_bf16_rne(v.y) << 16);
        }
    }

    // feat -> bf16 into fbf (stride 128): 2048 float4, 8 per thread
    #pragma unroll
    for (int p = 0; p < 8; ++p) {
        int q = t + p * 256;             // 0..2047
        int r = q >> 5;                  // 0..63
        int c4 = (q & 31) * 4;
        if (row0 + r < N_NODES) {
            float4 f = *(const float4*)(feat + (size_t)(row0 + r) * D_IN + c4);
            uint2 pk;
            pk.x = pack_bf16_rne(f.x) | (pack_bf16_rne(f.y) << 16);
            pk.y = pack_bf16_rne(f.z) | (pack_bf16_rne(f.w) << 16);
            ((uint2*)(fbf + (size_t)(row0 + r) * D_IN))[q & 31] = pk;
        }
    }
}

// ------ kernel 3 (fused): per-block SpMM gather -> LDS agg, then GEMM over K=256 -------
// out[N][256] = [fbf | agg] @ B[256][256]^T + bias.  (Verified round-2 structure.)
// Phase 1: quarter-wave per dst row, 16 contiguous 16B gathers per row from xbf
// (coalesced 256B/row), accumulate in regs, write XOR-swizzled bf16 Agg tile.
// Phase 2: BM=128, BN=256 (A read once), BK=32, 8 waves (2x4), swapped-operand
// mfma_f32_16x16x32_bf16; A = staged fbf (kt 0-3) then LDS Agg (kt 4-7).
// NEW vs round 2: nontemporal out-stores (don't evict xbf from L2/L3) and
// nontemporal csr/col loads (read-once streams). floatx4 (clang vector) used for
// the NT store — HIP_vector_type float4 is rejected by the builtin (round-6 bug).
#define BM 128
#define BN 256
#define BK 32
#define NTA 4   // K-steps covered by fbf
#define NT  8

__global__ __launch_bounds__(512, 2) void k_fused(const float* __restrict__ csr_w,
                                                  const int* __restrict__ col_idx,
                                                  const unsigned short* __restrict__ xbf,
                                                  const unsigned short* __restrict__ fbf,
                                                  const unsigned short* __restrict__ bmat,
                                                  const float* __restrict__ bias,
                                                  float* __restrict__ out) {
    __shared__ __align__(16) unsigned short Agg[BM * 128];     // 32 KiB, swizzled
    __shared__ __align__(16) unsigned short As[2][BM * BK];    // 16 KiB
    __shared__ __align__(16) unsigned short Bs[2][BN * BK];    // 32 KiB
    const int t    = threadIdx.x;
    const int lane = t & 63, wave = t >> 6;
    const int l16  = lane & 15, quad = lane >> 4;
    const int row0 = blockIdx.x * BM;

    // staging geometry: each wave's 64 lanes cover 16 rows x 4x16B chunks (linear LDS)
    const int a_r = wave * 16 + (lane >> 2);
    const int a_c = (lane & 3) * 8;                          // shorts
    int a_gr = row0 + a_r; if (a_gr >= N_NODES) a_gr = N_NODES - 1;  // clamp: garbage
    const unsigned short* gA  = fbf  + (size_t)a_gr * D_IN + a_c;    // rows never stored
    const unsigned short* gB0 = bmat + (size_t)a_r        * K_CAT + a_c;
    const unsigned short* gB1 = bmat + (size_t)(a_r + 128) * K_CAT + a_c;

#define STAGE_A(buf, tt) gload_lds16(gA + (tt) * BK, &As[buf][wave * 16 * BK])
#define STAGE_B(buf, tt) do {                                                 \
        gload_lds16(gB0 + (tt) * BK, &Bs[buf][(wave * 16)       * BK]);       \
        gload_lds16(gB1 + (tt) * BK, &Bs[buf][(wave * 16 + 128) * BK]);       \
    } while (0)

    // issue first K-step staging now; it flies during the gather phase
    STAGE_A(0, 0);
    STAGE_B(0, 0);

    // ---- phase 1: aggregate 128 rows into Agg (quarter-wave per row, 4 passes) ----
    const int ql = lane & 15, qb = lane & 48;
    #pragma unroll 1
    for (int p = 0; p < 4; ++p) {
        const int r  = p * 32 + wave * 4 + (lane >> 4);      // 0..127
        const int gr = row0 + r;
        int   c = 0; float w = 0.f;
        if (gr < N_NODES) {
            c = __builtin_nontemporal_load(col_idx + gr * DEG + ql);
            w = __builtin_nontemporal_load(csr_w   + gr * DEG + ql);
        }
        uint4 vv[DEG];
        #pragma unroll
        for (int e = 0; e < DEG; ++e) {
            int col = __shfl(c, qb | e);
            vv[e] = *(const uint4*)(xbf + (size_t)col * D_IN + ql * 8);
        }
        float a[8] = {0.f, 0.f, 0.f, 0.f, 0.f, 0.f, 0.f, 0.f};
        #pragma unroll
        for (int e = 0; e < DEG; ++e) {
            float we = __shfl(w, qb | e);
            uint4 v = vv[e];
            a[0] += we * bf16lo_to_f(v.x & 0xffffu);
            a[1] += we * bf16lo_to_f(v.x >> 16);
            a[2] += we * bf16lo_to_f(v.y & 0xffffu);
            a[3] += we * bf16lo_to_f(v.y >> 16);
            a[4] += we * bf16lo_to_f(v.z & 0xffffu);
            a[5] += we * bf16lo_to_f(v.z >> 16);
            a[6] += we * bf16lo_to_f(v.w & 0xffffu);
            a[7] += we * bf16lo_to_f(v.w >> 16);
        }
        uint4 pk;
        pk.x = pack_bf16_rne(a[0]) | (pack_bf16_rne(a[1]) << 16);
        pk.y = pack_bf16_rne(a[2]) | (pack_bf16_rne(a[3]) << 16);
        pk.z = pack_bf16_rne(a[4]) | (pack_bf16_rne(a[5]) << 16);
        pk.w = pack_bf16_rne(a[6]) | (pack_bf16_rne(a[7]) << 16);
        // swizzled write: shorts [r][ (ql*8) ^ ((r&7)<<3) ]
        *(uint4*)&Agg[r * 128 + ((ql * 8) ^ ((r & 7) << 3))] = pk;
    }

    // ---- phase 2: GEMM K-loop ----
    const int wr = wave >> 2, wc = wave & 3;                 // 2x4 wave grid, 64x64 each
    floatx4 acc[4][4];
    #pragma unroll
    for (int i = 0; i < 4; ++i)
        #pragma unroll
        for (int j = 0; j < 4; ++j)
            acc[i][j] = (floatx4){0.f, 0.f, 0.f, 0.f};

    __syncthreads();   // drains vmcnt(0): buf0 staged + Agg writes visible

    #pragma unroll
    for (int tt = 0; tt < NT; ++tt) {
        const int cur = tt & 1;
        if (tt + 1 < NTA) STAGE_A(cur ^ 1, tt + 1);          // prefetch next A (fbf half)
        if (tt + 1 < NT)  STAGE_B(cur ^ 1, tt + 1);          // prefetch next B

        short8 afr[4], bfr[4];
        if (tt < NTA) {
            #pragma unroll
            for (int i = 0; i < 4; ++i)
                afr[i] = *(const short8*)&As[cur][(wr * 64 + i * 16 + l16) * BK + quad * 8];
        } else {
            const int c0 = (tt - NTA) * 32 + quad * 8;
            #pragma unroll
            for (int i = 0; i < 4; ++i) {
                const int m = wr * 64 + i * 16 + l16;
                afr[i] = *(const short8*)&Agg[m * 128 + (c0 ^ ((m & 7) << 3))];
            }
        }
        #pragma unroll
        for (int j = 0; j < 4; ++j)
            bfr[j] = *(const short8*)&Bs[cur][(wc * 64 + j * 16 + l16) * BK + quad * 8];

        #pragma unroll
        for (int i = 0; i < 4; ++i)
            #pragma unroll
            for (int j = 0; j < 4; ++j)   // swapped: out-rows <- afr lanes, out-cols <- bfr regs
                acc[i][j] = __builtin_amdgcn_mfma_f32_16x16x32_bf16(bfr[j], afr[i], acc[i][j], 0, 0, 0);

        if (tt + 1 < NT) __syncthreads();
    }

    // epilogue: lane holds row m = l16 (+16i+64wr), cols quad*4..+3 (+16j+64wc)
    // nontemporal floatx4 stores: out is write-once, keep it out of L2/L3 so the
    // gather-hot xbf stays resident.
    #pragma unroll
    for (int j = 0; j < 4; ++j) {
        const int cg = wc * 64 + j * 16 + quad * 4;
        const floatx4 bv = *(const floatx4*)&bias[cg];
        #pragma unroll
        for (int i = 0; i < 4; ++i) {
            const int gr = row0 + wr * 64 + i * 16 + l16;
            if (gr < N_NODES) {
                floatx4 v = acc[i][j] + bv;
                __builtin_nontemporal_store(v, (floatx4*)(out + (size_t)gr * D_OUT + cg));
            }
        }
    }
#undef STAGE_A
#undef STAGE_B
}

extern "C" void kernel_launch(void* const* d_in, const int* in_sizes, int n_in,
                              void* d_out, int out_size, void* d_ws, size_t ws_size,
                              hipStream_t stream) {
    const float* feat    = (const float*)d_in[0];
    const float* topk_v  = (const float*)d_in[1];
    const float* csr_w   = (const float*)d_in[2];
    const float* w_neigh = (const float*)d_in[3];
    const float* w_self  = (const float*)d_in[4];
    const float* b_self  = (const float*)d_in[5];
    const int*   topk_i  = (const int*)d_in[6];
    // d_in[7] = indptr (fixed degree 16, unused), d_in[8] = indices
    const int*   indices = (const int*)d_in[8];
    float* out = (float*)d_out;

    // workspace layout (bf16): x[N*128] | f[N*128] | B[256*256]  (~51.4 MB)
    unsigned short* xbf  = (unsigned short*)d_ws;
    unsigned short* fbf  = xbf + (size_t)N_NODES * D_IN;
    unsigned short* bmat = fbf + (size_t)N_NODES * D_IN;

    k_packw<<<dim3(256), dim3(256), 0, stream>>>(w_self, w_neigh, bmat);
    k_densify<<<dim3((N_NODES + DROWS - 1) / DROWS), dim3(256), 0, stream>>>(topk_v, topk_i, feat, xbf, fbf);
    k_fused<<<dim3((N_NODES + BM - 1) / BM), dim3(512), 0, stream>>>(
        csr_w, indices, xbf, fbf, bmat, b_self, out);
}